// Round 1
// baseline (1039.143 us; speedup 1.0000x reference)
//
#include <hip/hip_runtime.h>

#define Bb 8
#define Cc 64
#define Tt 16
#define Hh 56
#define Ww 56
#define COUT 128
#define HW (Hh*Ww)            // 3136
#define THW (Tt*HW)           // 50176
#define NPG (32*THW)          // elements per (b,group) = 1,605,632

// ---------------------------------------------------------------------------
// K1: fused depthwise spatial 3x3 (pad 1) + temporal 3-tap (pad 1) conv.
// One thread computes 8 consecutive w outputs for one (b,c,t,h).
// z[b,c,t,h,w] = tb[c] + sum_{valid dt} tw[c,dt+1] *
//                ( sb[c] + sum_{dh,dw} sw[c,dh+1,dw+1] * x_pad[...] )
// ---------------------------------------------------------------------------
__global__ __launch_bounds__(256) void k1_dwconv(
    const float* __restrict__ x,  const float* __restrict__ sw,
    const float* __restrict__ sb, const float* __restrict__ tw,
    const float* __restrict__ tb, float* __restrict__ z)
{
  int idx = blockIdx.x * 256 + threadIdx.x;      // chunk index (8 w per chunk)
  int wchunk = idx % 7;
  int h  = (idx / 7) % Hh;
  int t  = (idx / (7 * Hh)) % Tt;
  int c  = (idx / (7 * Hh * Tt)) % Cc;
  int b  =  idx / (7 * Hh * Tt * Cc);
  int w0 = wchunk * 8;

  float s9[9];
#pragma unroll
  for (int k = 0; k < 9; ++k) s9[k] = sw[c * 9 + k];
  float t3[3];
#pragma unroll
  for (int k = 0; k < 3; ++k) t3[k] = tw[c * 3 + k];
  float sbc = sb[c], tbc = tb[c];

  const float* xb = x + ((long long)(b * Cc + c) * Tt) * HW;

  float acc[8];
#pragma unroll
  for (int j = 0; j < 8; ++j) acc[j] = tbc;

#pragma unroll
  for (int dt = -1; dt <= 1; ++dt) {
    int tt = t + dt;
    if (tt < 0 || tt >= Tt) continue;
    const float* xp = xb + tt * HW;
    float s[8];
#pragma unroll
    for (int j = 0; j < 8; ++j) s[j] = sbc;
#pragma unroll
    for (int dh = -1; dh <= 1; ++dh) {
      int hh = h + dh;
      if (hh < 0 || hh >= Hh) continue;
      const float* xr = xp + hh * Ww;
      float r[10];
#pragma unroll
      for (int j = 0; j < 10; ++j) {
        int wv = w0 - 1 + j;
        r[j] = (wv >= 0 && wv < Ww) ? xr[wv] : 0.0f;
      }
      float k0 = s9[(dh + 1) * 3 + 0];
      float k1 = s9[(dh + 1) * 3 + 1];
      float k2 = s9[(dh + 1) * 3 + 2];
#pragma unroll
      for (int j = 0; j < 8; ++j)
        s[j] = fmaf(k0, r[j], fmaf(k1, r[j + 1], fmaf(k2, r[j + 2], s[j])));
    }
    float tk = t3[dt + 1];
#pragma unroll
    for (int j = 0; j < 8; ++j) acc[j] = fmaf(tk, s[j], acc[j]);
  }

  float* zp = z + (long long)idx * 8;
  *(float4*)(zp)     = make_float4(acc[0], acc[1], acc[2], acc[3]);
  *(float4*)(zp + 4) = make_float4(acc[4], acc[5], acc[6], acc[7]);
}

// ---------------------------------------------------------------------------
// K2: pointwise GEMM on the fly; accumulate per-(b,group) sum / sumsq.
// One thread per (b,pos): z column (64) in registers, W (128x64) in LDS.
// ---------------------------------------------------------------------------
__global__ __launch_bounds__(256) void k2_stats(
    const float* __restrict__ z, const float* __restrict__ pw,
    const float* __restrict__ pb, float* __restrict__ stats)
{
  __shared__ float wlds[COUT * Cc];          // 32 KB
  for (int i = threadIdx.x; i < COUT * Cc; i += 256) wlds[i] = pw[i];
  __syncthreads();

  int b   = blockIdx.x / 196;
  int pos = (blockIdx.x % 196) * 256 + threadIdx.x;
  const float* zp = z + (long long)b * Cc * THW + pos;

  float zr[Cc];
#pragma unroll
  for (int c2 = 0; c2 < Cc; ++c2) zr[c2] = zp[(long long)c2 * THW];

  for (int g = 0; g < 4; ++g) {
    float s1 = 0.0f, s2 = 0.0f;
    for (int oi = 0; oi < 32; ++oi) {
      int o = g * 32 + oi;
      const float* wrow = &wlds[o * Cc];
      float d0 = 0, d1 = 0, d2 = 0, d3 = 0;
#pragma unroll
      for (int c2 = 0; c2 < Cc; c2 += 4) {
        d0 = fmaf(wrow[c2 + 0], zr[c2 + 0], d0);
        d1 = fmaf(wrow[c2 + 1], zr[c2 + 1], d1);
        d2 = fmaf(wrow[c2 + 2], zr[c2 + 2], d2);
        d3 = fmaf(wrow[c2 + 3], zr[c2 + 3], d3);
      }
      float d = ((d0 + d1) + (d2 + d3)) + pb[o];
      s1 += d;
      s2 = fmaf(d, d, s2);
    }
#pragma unroll
    for (int off = 32; off > 0; off >>= 1) {
      s1 += __shfl_xor(s1, off);
      s2 += __shfl_xor(s2, off);
    }
    if ((threadIdx.x & 63) == 0) {
      atomicAdd(&stats[(b * 4 + g) * 2 + 0], s1);
      atomicAdd(&stats[(b * 4 + g) * 2 + 1], s2);
    }
  }
}

// ---------------------------------------------------------------------------
// K3: recompute pointwise GEMM, normalize (GroupNorm) + affine + ReLU, store.
// ---------------------------------------------------------------------------
__global__ __launch_bounds__(256) void k3_norm(
    const float* __restrict__ z, const float* __restrict__ pw,
    const float* __restrict__ pb, const float* __restrict__ stats,
    const float* __restrict__ gnw, const float* __restrict__ gnb,
    float* __restrict__ out)
{
  __shared__ float wlds[COUT * Cc];
  for (int i = threadIdx.x; i < COUT * Cc; i += 256) wlds[i] = pw[i];
  __syncthreads();

  int b   = blockIdx.x / 196;
  int pos = (blockIdx.x % 196) * 256 + threadIdx.x;
  const float* zp = z + (long long)b * Cc * THW + pos;

  float zr[Cc];
#pragma unroll
  for (int c2 = 0; c2 < Cc; ++c2) zr[c2] = zp[(long long)c2 * THW];

  float* op = out + (long long)b * COUT * THW + pos;
  const float invN = 1.0f / (float)NPG;

  for (int g = 0; g < 4; ++g) {
    float m   = stats[(b * 4 + g) * 2 + 0] * invN;
    float var = stats[(b * 4 + g) * 2 + 1] * invN - m * m;
    float inv = rsqrtf(var + 1e-5f);
    for (int oi = 0; oi < 32; ++oi) {
      int o = g * 32 + oi;
      const float* wrow = &wlds[o * Cc];
      float d0 = 0, d1 = 0, d2 = 0, d3 = 0;
#pragma unroll
      for (int c2 = 0; c2 < Cc; c2 += 4) {
        d0 = fmaf(wrow[c2 + 0], zr[c2 + 0], d0);
        d1 = fmaf(wrow[c2 + 1], zr[c2 + 1], d1);
        d2 = fmaf(wrow[c2 + 2], zr[c2 + 2], d2);
        d3 = fmaf(wrow[c2 + 3], zr[c2 + 3], d3);
      }
      float d = ((d0 + d1) + (d2 + d3)) + pb[o];
      float v = fmaf((d - m) * inv, gnw[o], gnb[o]);
      op[(long long)o * THW] = v > 0.0f ? v : 0.0f;
    }
  }
}

// ---------------------------------------------------------------------------
extern "C" void kernel_launch(void* const* d_in, const int* in_sizes, int n_in,
                              void* d_out, int out_size, void* d_ws, size_t ws_size,
                              hipStream_t stream)
{
  const float* x   = (const float*)d_in[0];
  const float* sw  = (const float*)d_in[1];
  const float* sb  = (const float*)d_in[2];
  const float* tw  = (const float*)d_in[3];
  const float* tb  = (const float*)d_in[4];
  const float* pw  = (const float*)d_in[5];
  const float* pb  = (const float*)d_in[6];
  const float* gnw = (const float*)d_in[7];
  const float* gnb = (const float*)d_in[8];
  float* out = (float*)d_out;

  float* stats = (float*)d_ws;                       // 64 floats
  float* z     = (float*)((char*)d_ws + 256);        // 25,690,112 floats

  hipMemsetAsync(stats, 0, 64 * sizeof(float), stream);

  // K1: 8*64*16*56*7 = 3,211,264 chunks / 256 = 12,544 blocks
  k1_dwconv<<<12544, 256, 0, stream>>>(x, sw, sb, tw, tb, z);
  // K2/K3: 8 batches * (50176/256)=196 blocks
  k2_stats<<<1568, 256, 0, stream>>>(z, pw, pb, stats);
  k3_norm<<<1568, 256, 0, stream>>>(z, pw, pb, stats, gnw, gnb, out);
}

// Round 2
// 363.721 us; speedup vs baseline: 2.8570x; 2.8570x over previous
//
#include <hip/hip_runtime.h>

#define Bb 8
#define Cc 64
#define Tt 16
#define Hh 56
#define Ww 56
#define COUT 128
#define HW (Hh*Ww)            // 3136
#define THW (Tt*HW)           // 50176
#define NPG ((double)(32*THW))

// ---------------------------------------------------------------------------
// K1: fused depthwise spatial 3x3 + temporal 3-tap, ring-buffered in LDS.
// One block per (b,c). Each raw plane is loaded from HBM exactly once.
// ---------------------------------------------------------------------------
__global__ __launch_bounds__(256) void k1_dwconv(
    const float* __restrict__ x,  const float* __restrict__ sw,
    const float* __restrict__ sb, const float* __restrict__ tw,
    const float* __restrict__ tb, float* __restrict__ z)
{
  __shared__ float raw[HW];          // 12.25 KB
  __shared__ float ring[3][HW];      // 36.75 KB

  const int tid = threadIdx.x;
  const int c = blockIdx.x & 63;
  const int b = blockIdx.x >> 6;

  float s9[9];
#pragma unroll
  for (int k = 0; k < 9; ++k) s9[k] = sw[c * 9 + k];
  float t3a[3];
#pragma unroll
  for (int k = 0; k < 3; ++k) t3a[k] = tw[c * 3 + k];
  const float sbc = sb[c], tbc = tb[c];

  const float* xbase = x + (size_t)(b * Cc + c) * THW;
  float*       zbase = z + (size_t)(b * Cc + c) * THW;

  for (int tt = 0; tt < Tt; ++tt) {
    // ---- load raw plane tt (coalesced float4) ----
    const float* xp = xbase + tt * HW;
    for (int f = tid; f < HW / 4; f += 256)
      *(float4*)&raw[f * 4] = *(const float4*)(xp + f * 4);
    __syncthreads();

    // ---- spatial 3x3 conv: raw -> ring[tt%3] ----
    float* rg = ring[tt % 3];
    for (int q = tid; q < HW / 4; q += 256) {
      int h  = q / 14;
      int w0 = (q - h * 14) * 4;
      float4 sacc = make_float4(sbc, sbc, sbc, sbc);
#pragma unroll
      for (int dh = -1; dh <= 1; ++dh) {
        int hh = h + dh;
        if (hh < 0 || hh > Hh - 1) continue;
        const float* rr = &raw[hh * Ww];
        float4 mv = *(const float4*)(rr + w0);
        float lf = (w0 > 0)      ? rr[w0 - 1] : 0.0f;
        float rt = (w0 < Ww - 4) ? rr[w0 + 4] : 0.0f;
        float k0 = s9[(dh + 1) * 3 + 0];
        float k1 = s9[(dh + 1) * 3 + 1];
        float k2 = s9[(dh + 1) * 3 + 2];
        sacc.x = fmaf(k0, lf,   fmaf(k1, mv.x, fmaf(k2, mv.y, sacc.x)));
        sacc.y = fmaf(k0, mv.x, fmaf(k1, mv.y, fmaf(k2, mv.z, sacc.y)));
        sacc.z = fmaf(k0, mv.y, fmaf(k1, mv.z, fmaf(k2, mv.w, sacc.z)));
        sacc.w = fmaf(k0, mv.z, fmaf(k1, mv.w, fmaf(k2, rt,   sacc.w)));
      }
      *(float4*)&rg[q * 4] = sacc;
    }
    __syncthreads();

    // ---- temporal emit t_out = tt-1 ----
    if (tt >= 1) {
      int t_out = tt - 1;
      float* zp = zbase + t_out * HW;
      for (int q = tid; q < HW / 4; q += 256) {
        float4 a = make_float4(tbc, tbc, tbc, tbc);
#pragma unroll
        for (int dt = -1; dt <= 1; ++dt) {
          int ti = t_out + dt;
          if (ti < 0 || ti > Tt - 1) continue;
          float tk = t3a[dt + 1];
          float4 v = *(const float4*)&ring[ti % 3][q * 4];
          a.x = fmaf(tk, v.x, a.x);
          a.y = fmaf(tk, v.y, a.y);
          a.z = fmaf(tk, v.z, a.z);
          a.w = fmaf(tk, v.w, a.w);
        }
        *(float4*)(zp + q * 4) = a;
      }
    }
    __syncthreads();
  }
  // final plane t_out = 15 (ring holds planes 13,14,15)
  {
    int t_out = Tt - 1;
    float* zp = zbase + t_out * HW;
    for (int q = tid; q < HW / 4; q += 256) {
      float4 a = make_float4(tbc, tbc, tbc, tbc);
#pragma unroll
      for (int dt = -1; dt <= 0; ++dt) {
        int ti = t_out + dt;
        float tk = t3a[dt + 1];
        float4 v = *(const float4*)&ring[ti % 3][q * 4];
        a.x = fmaf(tk, v.x, a.x);
        a.y = fmaf(tk, v.y, a.y);
        a.z = fmaf(tk, v.z, a.z);
        a.w = fmaf(tk, v.w, a.w);
      }
      *(float4*)(zp + q * 4) = a;
    }
  }
}

// ---------------------------------------------------------------------------
// Shared GEMM tile: 128 pos x 128 out per block, 8x8 per thread.
// zt[k][p] (64x128), wt[k][o] (64x128, transposed at stage time).
// ---------------------------------------------------------------------------
#define GEMM_STAGE_AND_ACC()                                                   \
  __shared__ float zt[64 * 128];                                               \
  __shared__ float wt[64 * 128];                                               \
  const int tid = threadIdx.x;                                                 \
  const int b  = blockIdx.x / 392;                                             \
  const int p0 = (blockIdx.x - b * 392) * 128;                                 \
  if (tid < 128) {                                                             \
    const float* wr = pw + tid * 64;                                           \
    _Pragma("unroll")                                                          \
    for (int k = 0; k < 64; k += 4) {                                          \
      float4 v = *(const float4*)(wr + k);                                     \
      wt[(k + 0) * 128 + tid] = v.x;                                           \
      wt[(k + 1) * 128 + tid] = v.y;                                           \
      wt[(k + 2) * 128 + tid] = v.z;                                           \
      wt[(k + 3) * 128 + tid] = v.w;                                           \
    }                                                                          \
  }                                                                            \
  {                                                                            \
    const float* zb = z + (size_t)b * Cc * THW + p0;                           \
    for (int f = tid; f < 2048; f += 256) {                                    \
      int k  = f >> 5;                                                         \
      int po = (f & 31) << 2;                                                  \
      *(float4*)&zt[k * 128 + po] = *(const float4*)(zb + (size_t)k * THW + po);\
    }                                                                          \
  }                                                                            \
  __syncthreads();                                                             \
  const int tx = tid & 15, ty = tid >> 4;                                      \
  float acc[8][8];                                                             \
  _Pragma("unroll")                                                            \
  for (int oi = 0; oi < 8; ++oi)                                               \
    _Pragma("unroll")                                                          \
    for (int pj = 0; pj < 8; ++pj) acc[oi][pj] = 0.0f;                         \
  {                                                                            \
    const float* ztp = &zt[tx * 8];                                            \
    const float* wtp = &wt[ty * 8];                                            \
    _Pragma("unroll 4")                                                        \
    for (int k = 0; k < 64; ++k) {                                             \
      float4 za = *(const float4*)(ztp + k * 128);                             \
      float4 zc = *(const float4*)(ztp + k * 128 + 4);                         \
      float4 wa = *(const float4*)(wtp + k * 128);                             \
      float4 wc = *(const float4*)(wtp + k * 128 + 4);                         \
      float zr[8] = {za.x, za.y, za.z, za.w, zc.x, zc.y, zc.z, zc.w};          \
      float wreg[8] = {wa.x, wa.y, wa.z, wa.w, wc.x, wc.y, wc.z, wc.w};        \
      _Pragma("unroll")                                                        \
      for (int oi = 0; oi < 8; ++oi)                                           \
        _Pragma("unroll")                                                      \
        for (int pj = 0; pj < 8; ++pj)                                         \
          acc[oi][pj] = fmaf(wreg[oi], zr[pj], acc[oi][pj]);                   \
    }                                                                          \
  }

// K2: GEMM -> per-(b,group) sum / sumsq (double atomics).
__global__ __launch_bounds__(256) void k2_stats(
    const float* __restrict__ z, const float* __restrict__ pw,
    const float* __restrict__ pb, double* __restrict__ stats)
{
  GEMM_STAGE_AND_ACC();

  float s1 = 0.0f, s2 = 0.0f;
#pragma unroll
  for (int oi = 0; oi < 8; ++oi) {
    float bb = pb[ty * 8 + oi];
#pragma unroll
    for (int pj = 0; pj < 8; ++pj) {
      float d = acc[oi][pj] + bb;
      s1 += d;
      s2 = fmaf(d, d, s2);
    }
  }
#pragma unroll
  for (int off = 32; off; off >>= 1) {
    s1 += __shfl_xor(s1, off);
    s2 += __shfl_xor(s2, off);
  }
  if ((tid & 63) == 0) {
    int g = ty >> 2;   // 8 outs per ty, 32 outs per group; wave-uniform
    atomicAdd(&stats[(b * 4 + g) * 2 + 0], (double)s1);
    atomicAdd(&stats[(b * 4 + g) * 2 + 1], (double)s2);
  }
}

// K3: GEMM recompute -> GroupNorm + affine + ReLU -> out.
__global__ __launch_bounds__(256) void k3_norm(
    const float* __restrict__ z, const float* __restrict__ pw,
    const float* __restrict__ pb, const double* __restrict__ stats,
    const float* __restrict__ gnw, const float* __restrict__ gnb,
    float* __restrict__ out)
{
  GEMM_STAGE_AND_ACC();

  const int g = ty >> 2;
  double s1 = stats[(b * 4 + g) * 2 + 0];
  double s2 = stats[(b * 4 + g) * 2 + 1];
  double md = s1 / NPG;
  double vard = s2 / NPG - md * md;
  float m = (float)md;
  float inv = rsqrtf((float)vard + 1e-5f);

  float* ob = out + (size_t)b * COUT * THW + p0 + tx * 8;
#pragma unroll
  for (int oi = 0; oi < 8; ++oi) {
    int o = ty * 8 + oi;
    float A = inv * gnw[o];
    float B = fmaf(pb[o] - m, A, gnb[o]);
    float v0 = fmaf(acc[oi][0], A, B); v0 = v0 > 0.0f ? v0 : 0.0f;
    float v1 = fmaf(acc[oi][1], A, B); v1 = v1 > 0.0f ? v1 : 0.0f;
    float v2 = fmaf(acc[oi][2], A, B); v2 = v2 > 0.0f ? v2 : 0.0f;
    float v3 = fmaf(acc[oi][3], A, B); v3 = v3 > 0.0f ? v3 : 0.0f;
    float v4 = fmaf(acc[oi][4], A, B); v4 = v4 > 0.0f ? v4 : 0.0f;
    float v5 = fmaf(acc[oi][5], A, B); v5 = v5 > 0.0f ? v5 : 0.0f;
    float v6 = fmaf(acc[oi][6], A, B); v6 = v6 > 0.0f ? v6 : 0.0f;
    float v7 = fmaf(acc[oi][7], A, B); v7 = v7 > 0.0f ? v7 : 0.0f;
    *(float4*)(ob + (size_t)o * THW + 0) = make_float4(v0, v1, v2, v3);
    *(float4*)(ob + (size_t)o * THW + 4) = make_float4(v4, v5, v6, v7);
  }
}

// ---------------------------------------------------------------------------
extern "C" void kernel_launch(void* const* d_in, const int* in_sizes, int n_in,
                              void* d_out, int out_size, void* d_ws, size_t ws_size,
                              hipStream_t stream)
{
  const float* x   = (const float*)d_in[0];
  const float* sw  = (const float*)d_in[1];
  const float* sb  = (const float*)d_in[2];
  const float* tw  = (const float*)d_in[3];
  const float* tb  = (const float*)d_in[4];
  const float* pw  = (const float*)d_in[5];
  const float* pb  = (const float*)d_in[6];
  const float* gnw = (const float*)d_in[7];
  const float* gnb = (const float*)d_in[8];
  float* out = (float*)d_out;

  double* stats = (double*)d_ws;                     // 64 doubles = 512 B
  float*  z     = (float*)((char*)d_ws + 512);       // 25,690,112 floats

  hipMemsetAsync(stats, 0, 64 * sizeof(double), stream);

  k1_dwconv<<<Bb * Cc, 256, 0, stream>>>(x, sw, sb, tw, tb, z);   // 512 blocks
  k2_stats<<<Bb * 392, 256, 0, stream>>>(z, pw, pb, stats);       // 3136 blocks
  k3_norm <<<Bb * 392, 256, 0, stream>>>(z, pw, pb, stats, gnw, gnb, out);
}